// Round 5
// baseline (88.441 us; speedup 1.0000x reference)
//
#include <hip/hip_runtime.h>
#include <math.h>

#define BLK  256
#define BLKM 1024

constexpr int N_IMG = 32;
constexpr int P_PRI = 8732;
constexpr int C_CLS = 81;
constexpr int N_OBJ = 24;
constexpr int RPB   = 64;                         // rows per k_main block
constexpr int PB2   = (P_PRI + RPB - 1) / RPB;    // 137 blocks per image
constexpr int NBLK2 = PB2 * N_IMG;                // 4384 partial slots
constexpr int LROW  = 84;                         // padded LDS row stride (floats)
constexpr int NLD   = 6;                          // staging float4s per thread

// ---------------------------------------------------------------------------
// Kernel 1: per (image, object): argmax IoU over priors (first max index).
// Also zeroes npos (block x==0).
// ---------------------------------------------------------------------------
__global__ void k_obj_match(const float* __restrict__ boxes,
                            const float* __restrict__ priors,
                            int* __restrict__ prior_for_obj,
                            int* __restrict__ npos) {
    const int o = blockIdx.x;
    const int n = blockIdx.y;
    const int tid = threadIdx.x;

    if (o == 0 && tid == 0) npos[n] = 0;

    const float x1 = boxes[(n * N_OBJ + o) * 4 + 0];
    const float y1 = boxes[(n * N_OBJ + o) * 4 + 1];
    const float x2 = boxes[(n * N_OBJ + o) * 4 + 2];
    const float y2 = boxes[(n * N_OBJ + o) * 4 + 3];
    const float ab = (x2 - x1) * (y2 - y1);

    const float4* pr4 = (const float4*)priors;

    float bv = -1.0f;
    int   bi = P_PRI;
    for (int p = tid; p < P_PRI; p += BLK) {
        const float4 c = pr4[p];
        const float px1 = c.x - c.z / 2.0f, py1 = c.y - c.w / 2.0f;
        const float px2 = c.x + c.z / 2.0f, py2 = c.y + c.w / 2.0f;
        const float pa  = (px2 - px1) * (py2 - py1);
        const float lox = fmaxf(x1, px1), loy = fmaxf(y1, py1);
        const float hix = fminf(x2, px2), hiy = fminf(y2, py2);
        const float iw = fmaxf(hix - lox, 0.0f), ih = fmaxf(hiy - loy, 0.0f);
        const float inter = iw * ih;
        const float iou = inter / (ab + pa - inter);
        if (iou > bv) { bv = iou; bi = p; }            // ascending p keeps first max
    }

    __shared__ float sv[BLK];
    __shared__ int   si[BLK];
    sv[tid] = bv; si[tid] = bi;
    __syncthreads();
    for (int s = BLK / 2; s > 0; s >>= 1) {
        if (tid < s) {
            const float v2 = sv[tid + s]; const int i2 = si[tid + s];
            if (v2 > sv[tid] || (v2 == sv[tid] && i2 < si[tid])) { sv[tid] = v2; si[tid] = i2; }
        }
        __syncthreads();
    }
    if (tid == 0) prior_for_obj[n * N_OBJ + o] = si[0];
}

// ---------------------------------------------------------------------------
// Kernel 2: fused matching + softmax-CE + CIoU. 64 rows/block, 4 threads/row.
// Match and pfo-scan split across the quad's 4 lanes (6 objects each),
// combined by shfl with exact first-max / last-writer-wins semantics.
// ---------------------------------------------------------------------------
__global__ void __launch_bounds__(BLK, 7)
k_main(const float* __restrict__ locs,
       const float* __restrict__ scores,
       const float* __restrict__ boxes,
       const int*   __restrict__ labels,
       const float* __restrict__ priors,
       const int*   __restrict__ prior_for_obj,
       float* __restrict__ conf_neg,
       int*   __restrict__ npos,
       float* __restrict__ partial_conf,
       float* __restrict__ partial_loc) {
    __shared__ float sdata[RPB * LROW];   // 64*84*4 = 21504 B
    __shared__ int   pfo[N_OBJ];
    __shared__ int   slab[N_OBJ];
    __shared__ float wred[4][4];

    const int n   = blockIdx.y;
    const int r0  = blockIdx.x * RPB;
    const int tid = threadIdx.x;
    const int rows = min(RPB, P_PRI - r0);         // 64 or 28 (multiple of 4)
    const int nvec = (rows * C_CLS) >> 2;

    // ---- issue staging loads (coalesced float4) early ----
    const float4* src = (const float4*)(scores + ((size_t)n * P_PRI + r0) * C_CLS);
    float4 ld[NLD];
#pragma unroll
    for (int k = 0; k < NLD; ++k) {
        const int i = tid + k * BLK;
        if (i < nvec) ld[k] = src[i];
    }

    if (tid < N_OBJ) pfo[tid] = prior_for_obj[n * N_OBJ + tid];
    if (tid >= 64 && tid < 64 + N_OBJ) slab[tid - 64] = labels[n * N_OBJ + (tid - 64)];

    const int row = tid >> 2;
    const int q   = tid & 3;
    const int p   = r0 + row;
    const int psafe = (p < P_PRI) ? p : (P_PRI - 1);
    const float4 c = ((const float4*)priors)[psafe];
    const float px1 = c.x - c.z / 2.0f, py1 = c.y - c.w / 2.0f;
    const float px2 = c.x + c.z / 2.0f, py2 = c.y + c.w / 2.0f;
    const float pa  = (px2 - px1) * (py2 - py1);

    // ---- match: this lane handles objects [q*6, q*6+6) ----
    const float4* bxg = (const float4*)(boxes + (size_t)n * N_OBJ * 4);
    float bv = -1.0f;
    int   bo = q * 6;
#pragma unroll
    for (int j = 0; j < 6; ++j) {
        const int o = q * 6 + j;
        const float4 b = bxg[o];
        const float lox = fmaxf(b.x, px1), loy = fmaxf(b.y, py1);
        const float hix = fminf(b.z, px2), hiy = fminf(b.w, py2);
        const float iw = fmaxf(hix - lox, 0.0f), ih = fmaxf(hiy - loy, 0.0f);
        const float inter = iw * ih;
        const float ab = (b.z - b.x) * (b.w - b.y);
        const float iou = inter / (ab + pa - inter);
        if (iou > bv) { bv = iou; bo = o; }            // ascending keeps first max
    }
#pragma unroll
    for (int m = 1; m < 4; m <<= 1) {                  // quad combine: first-max
        const float v2 = __shfl_xor(bv, m);
        const int   o2 = __shfl_xor(bo, m);
        if (v2 > bv || (v2 == bv && o2 < bo)) { bv = v2; bo = o2; }
    }

    // ---- write staged data into padded LDS rows ----
#pragma unroll
    for (int k = 0; k < NLD; ++k) {
        const int i = tid + k * BLK;
        if (i < nvec) {
            const int f  = i * 4;
            const int r  = (int)((unsigned)f / 81u);
            const int cc = f - r * 81;
            const int base = r * LROW + cc;
            const float vv[4] = {ld[k].x, ld[k].y, ld[k].z, ld[k].w};
#pragma unroll
            for (int j = 0; j < 4; ++j) {
                int a = base + j;
                if (cc + j >= 81) a += (LROW - C_CLS);   // hop over pad to next row
                sdata[a] = vv[j];
            }
        }
    }
    __syncthreads();

    // ---- forced-prior overwrite: lane scans its 6, keep largest matching o ----
    int fo = -1;
#pragma unroll
    for (int j = 0; j < 6; ++j) {
        const int o = q * 6 + j;
        if (pfo[o] == p) fo = o;                       // ascending: keeps largest
    }
#pragma unroll
    for (int m = 1; m < 4; m <<= 1) fo = max(fo, __shfl_xor(fo, m));

    int   obj = (fo >= 0) ? fo : bo;
    float ov  = (fo >= 0) ? 1.0f : bv;

    // ---- quarter-row exp sum (no max pass) ----
    float s = 0.0f;
    const float* rbase = sdata + row * LROW;
    if (row < rows) {
        const float4* rv = (const float4*)(rbase + 20 * q);
        float a0 = 0.0f, a1 = 0.0f;
#pragma unroll
        for (int i = 0; i < 5; ++i) {
            const float4 v = rv[i];
            a0 += __expf(v.x) + __expf(v.y);
            a1 += __expf(v.z) + __expf(v.w);
        }
        s = a0 + a1;
        if (q == 3) s += __expf(rbase[80]);
    }
    s += __shfl_xor(s, 1);
    s += __shfl_xor(s, 2);                             // row total in all 4 lanes

    int cls = slab[obj];
    if (ov < 0.5f) cls = 0;

    float confpos = 0.0f, locv = 0.0f;
    int   cnt1 = 0;
    if (q == 0 && row < rows) {
        const float conf = __logf(s) - rbase[cls];
        const bool pos = (cls != 0);
        conf_neg[n * P_PRI + p] = pos ? 0.0f : fmaxf(conf, 0.0f);
        if (pos) {
            cnt1 = 1;
            confpos = conf;
            const float4 g = ((const float4*)locs)[(size_t)n * P_PRI + p];
            const float cx = g.x * c.z / 10.0f + c.x;
            const float cy = g.y * c.w / 10.0f + c.y;
            const float w  = expf(g.z / 5.0f) * c.z;
            const float hh = expf(g.w / 5.0f) * c.w;
            const float b1x1 = cx - w / 2.0f, b1y1 = cy - hh / 2.0f;
            const float b1x2 = cx + w / 2.0f, b1y2 = cy + hh / 2.0f;

            const float4 tb = bxg[obj];
            const float w1 = b1x2 - b1x1, h1 = b1y2 - b1y1;
            const float w2 = tb.z - tb.x, h2 = tb.w - tb.y;
            const float area1 = w1 * h1,  area2 = w2 * h2;
            const float c1x = (b1x2 + b1x1) / 2.0f, c1y = (b1y2 + b1y1) / 2.0f;
            const float c2x = (tb.z + tb.x) / 2.0f, c2y = (tb.w + tb.y) / 2.0f;
            const float inw = fmaxf(fminf(b1x2, tb.z) - fmaxf(b1x1, tb.x), 0.0f);
            const float inh = fmaxf(fminf(b1y2, tb.w) - fmaxf(b1y1, tb.y), 0.0f);
            const float owd = fmaxf(fmaxf(b1x2, tb.z) - fminf(b1x1, tb.x), 0.0f);
            const float ohd = fmaxf(fmaxf(b1y2, tb.w) - fminf(b1y1, tb.y), 0.0f);
            const float inner_diag = (c2x - c1x) * (c2x - c1x) + (c2y - c1y) * (c2y - c1y);
            const float outer_diag = owd * owd + ohd * ohd;
            const float inner = inw * inh;
            const float iou = inner / (area1 + area2 - inner);
            const float K = 0.40528473456935108577551785283891f; // 4/pi^2
            const float dat = atanf(w2 / h2) - atanf(w1 / h1);
            const float v = K * dat * dat;
            const float alpha = v / (1.0f - iou + v);
            locv = 1.0f - iou + inner_diag / outer_diag + alpha * v;
        }
    }

    // ---- block reduction: shfl within wave, tiny LDS across 4 waves ----
#pragma unroll
    for (int off = 32; off > 0; off >>= 1) {
        confpos += __shfl_down(confpos, off);
        locv    += __shfl_down(locv, off);
        cnt1    += __shfl_down(cnt1, off);
    }
    const int wid = tid >> 6;
    if ((tid & 63) == 0) {
        wred[wid][0] = confpos; wred[wid][1] = locv; wred[wid][2] = (float)cnt1;
    }
    __syncthreads();
    if (tid == 0) {
        float a = 0.0f, b = 0.0f, d = 0.0f;
#pragma unroll
        for (int w2 = 0; w2 < 4; ++w2) { a += wred[w2][0]; b += wred[w2][1]; d += wred[w2][2]; }
        const int slot = n * gridDim.x + blockIdx.x;
        partial_conf[slot] = a;
        partial_loc [slot] = b;
        atomicAdd(&npos[n], (int)d);
    }
}

// ---------------------------------------------------------------------------
// Kernel 3: per image, exact top-k sum of conf_neg (k=3*n_pos) via 31-round
// bitwise radix-select; values in registers; ballot/popc counts; 1 barrier/rd.
// ---------------------------------------------------------------------------
__global__ void __launch_bounds__(BLKM)
k_mine(const float* __restrict__ conf_neg,
       const int*   __restrict__ npos,
       float* __restrict__ hardneg) {
    __shared__ int   wcnt[2][BLKM / 64];
    __shared__ float wsum[BLKM / 64];

    const int n    = blockIdx.x;
    const int tid  = threadIdx.x;
    const int wid  = tid >> 6;
    const int lane = tid & 63;

    unsigned v[9];
#pragma unroll
    for (int k = 0; k < 9; ++k) {
        const int p = tid + k * BLKM;
        v[k] = (p < P_PRI) ? __float_as_uint(conf_neg[n * P_PRI + p]) : 0u;
    }

    int k0 = 3 * npos[n];
    if (k0 > P_PRI) k0 = P_PRI;
    if (k0 <= 0) { if (tid == 0) hardneg[n] = 0.0f; return; }

    unsigned prefix = 0u;
    int kk = k0;
    for (int bit = 30; bit >= 0; --bit) {          // bit31 (sign) always 0
        const unsigned hi = (prefix >> bit) | 1u;
        int cnt = 0;
#pragma unroll
        for (int k = 0; k < 9; ++k)
            cnt += __popcll(__ballot((v[k] >> bit) == hi));
        if (lane == 0) wcnt[bit & 1][wid] = cnt;
        __syncthreads();
        int tot = 0;
#pragma unroll
        for (int w = 0; w < BLKM / 64; ++w) tot += wcnt[bit & 1][w];
        if (tot >= kk) prefix |= (1u << bit);
        else           kk -= tot;
    }

    float psum = 0.0f; int pcnt = 0;
#pragma unroll
    for (int k = 0; k < 9; ++k) {
        if (v[k] > prefix) { psum += __uint_as_float(v[k]); ++pcnt; }
    }
#pragma unroll
    for (int off = 32; off > 0; off >>= 1) {
        psum += __shfl_down(psum, off);
        pcnt += __shfl_down(pcnt, off);
    }
    __syncthreads();
    if (lane == 0) { wsum[wid] = psum; wcnt[0][wid] = pcnt; }
    __syncthreads();
    if (tid == 0) {
        float S = 0.0f; int C = 0;
#pragma unroll
        for (int w = 0; w < BLKM / 64; ++w) { S += wsum[w]; C += wcnt[0][w]; }
        hardneg[n] = S + (float)(k0 - C) * __uint_as_float(prefix);
    }
}

// ---------------------------------------------------------------------------
// Kernel 4: final deterministic reduction to the scalar loss.
// ---------------------------------------------------------------------------
__global__ void k_final(const float* __restrict__ partial_conf,
                        const float* __restrict__ partial_loc,
                        const int*   __restrict__ npos,
                        const float* __restrict__ hardneg,
                        float* __restrict__ out) {
    __shared__ float s1[BLK], s2[BLK], s3[BLK];
    __shared__ int   si[BLK];
    const int tid = threadIdx.x;

    float c = 0.0f, l = 0.0f, h = 0.0f;
    int np = 0;
    for (int i = tid; i < NBLK2; i += BLK) { c += partial_conf[i]; l += partial_loc[i]; }
    if (tid < N_IMG) { h = hardneg[tid]; np = npos[tid]; }

    s1[tid] = c; s2[tid] = l; s3[tid] = h; si[tid] = np;
    __syncthreads();
    for (int s = BLK / 2; s > 0; s >>= 1) {
        if (tid < s) { s1[tid] += s1[tid + s]; s2[tid] += s2[tid + s];
                       s3[tid] += s3[tid + s]; si[tid] += si[tid + s]; }
        __syncthreads();
    }
    if (tid == 0) {
        const float npt = (float)si[0];
        const float conf_loss = (s3[0] + s1[0]) / npt;
        const float loc_loss  = s2[0] / npt;
        out[0] = conf_loss + loc_loss;   // ALPHA = 1
    }
}

// ---------------------------------------------------------------------------
extern "C" void kernel_launch(void* const* d_in, const int* in_sizes, int n_in,
                              void* d_out, int out_size, void* d_ws, size_t ws_size,
                              hipStream_t stream) {
    const float* locs   = (const float*)d_in[0];  // [N,P,4]
    const float* scores = (const float*)d_in[1];  // [N,P,C]
    const float* boxes  = (const float*)d_in[2];  // [N,NOBJ,4]
    const int*   labels = (const int*)  d_in[3];  // [N,NOBJ]
    const float* priors = (const float*)d_in[4];  // [P,4]
    float* out = (float*)d_out;

    char* w = (char*)d_ws;
    float* conf_neg      = (float*)w; w += (size_t)N_IMG * P_PRI * 4;
    int*   prior_for_obj = (int*)w;   w += (size_t)N_IMG * N_OBJ * 4;
    int*   npos          = (int*)w;   w += (size_t)N_IMG * 4;
    float* partial_conf  = (float*)w; w += (size_t)NBLK2 * 4;
    float* partial_loc   = (float*)w; w += (size_t)NBLK2 * 4;
    float* hardneg       = (float*)w; w += (size_t)N_IMG * 4;

    dim3 gridO(N_OBJ, N_IMG);
    k_obj_match<<<gridO, BLK, 0, stream>>>(boxes, priors, prior_for_obj, npos);

    dim3 gridM(PB2, N_IMG);
    k_main<<<gridM, BLK, 0, stream>>>(locs, scores, boxes, labels, priors,
                                      prior_for_obj, conf_neg, npos,
                                      partial_conf, partial_loc);

    k_mine<<<N_IMG, BLKM, 0, stream>>>(conf_neg, npos, hardneg);

    k_final<<<1, BLK, 0, stream>>>(partial_conf, partial_loc, npos, hardneg, out);
}

// Round 6
// 86.031 us; speedup vs baseline: 1.0280x; 1.0280x over previous
//
#include <hip/hip_runtime.h>
#include <math.h>

#define BLK  256
#define BLKM 1024

constexpr int N_IMG = 32;
constexpr int P_PRI = 8732;
constexpr int C_CLS = 81;
constexpr int N_OBJ = 24;
constexpr int RPB   = 64;                         // rows per k_main block (4 lanes/row)
constexpr int PB2   = (P_PRI + RPB - 1) / RPB;    // 137 blocks per image
constexpr int NBLK2 = PB2 * N_IMG;                // 4384 partial slots

// ---------------------------------------------------------------------------
// Kernel 1: per (image, object): argmax IoU over priors (first max index).
// Also zeroes npos (block x==0).
// ---------------------------------------------------------------------------
__global__ void k_obj_match(const float* __restrict__ boxes,
                            const float* __restrict__ priors,
                            int* __restrict__ prior_for_obj,
                            int* __restrict__ npos) {
    const int o = blockIdx.x;
    const int n = blockIdx.y;
    const int tid = threadIdx.x;

    if (o == 0 && tid == 0) npos[n] = 0;

    const float x1 = boxes[(n * N_OBJ + o) * 4 + 0];
    const float y1 = boxes[(n * N_OBJ + o) * 4 + 1];
    const float x2 = boxes[(n * N_OBJ + o) * 4 + 2];
    const float y2 = boxes[(n * N_OBJ + o) * 4 + 3];
    const float ab = (x2 - x1) * (y2 - y1);

    const float4* pr4 = (const float4*)priors;

    float bv = -1.0f;
    int   bi = P_PRI;
    for (int p = tid; p < P_PRI; p += BLK) {
        const float4 c = pr4[p];
        const float px1 = c.x - c.z / 2.0f, py1 = c.y - c.w / 2.0f;
        const float px2 = c.x + c.z / 2.0f, py2 = c.y + c.w / 2.0f;
        const float pa  = (px2 - px1) * (py2 - py1);
        const float lox = fmaxf(x1, px1), loy = fmaxf(y1, py1);
        const float hix = fminf(x2, px2), hiy = fminf(y2, py2);
        const float iw = fmaxf(hix - lox, 0.0f), ih = fmaxf(hiy - loy, 0.0f);
        const float inter = iw * ih;
        const float iou = inter / (ab + pa - inter);
        if (iou > bv) { bv = iou; bi = p; }            // ascending p keeps first max
    }

    __shared__ float sv[BLK];
    __shared__ int   si[BLK];
    sv[tid] = bv; si[tid] = bi;
    __syncthreads();
    for (int s = BLK / 2; s > 0; s >>= 1) {
        if (tid < s) {
            const float v2 = sv[tid + s]; const int i2 = si[tid + s];
            if (v2 > sv[tid] || (v2 == sv[tid] && i2 < si[tid])) { sv[tid] = v2; si[tid] = i2; }
        }
        __syncthreads();
    }
    if (tid == 0) prior_for_obj[n * N_OBJ + o] = si[0];
}

// ---------------------------------------------------------------------------
// Kernel 2: fused matching + softmax-CE + CIoU. NO LDS staging.
// 4 lanes per row; lane q reads floats c = q+4i of its row directly from
// global (16B consecutive per quad per step -> coalesced within the quad).
// exp-sum and x[cls] selected in the same sweep; 2-shfl quad reductions.
// ---------------------------------------------------------------------------
__global__ void __launch_bounds__(BLK)
k_main(const float* __restrict__ locs,
       const float* __restrict__ scores,
       const float* __restrict__ boxes,
       const int*   __restrict__ labels,
       const float* __restrict__ priors,
       const int*   __restrict__ prior_for_obj,
       float* __restrict__ conf_neg,
       int*   __restrict__ npos,
       float* __restrict__ partial_conf,
       float* __restrict__ partial_loc) {
    __shared__ int   pfo[N_OBJ];
    __shared__ int   slab[N_OBJ];
    __shared__ float wred[4][4];

    const int n   = blockIdx.y;
    const int r0  = blockIdx.x * RPB;
    const int tid = threadIdx.x;
    const int rows = min(RPB, P_PRI - r0);

    if (tid < N_OBJ) pfo[tid] = prior_for_obj[n * N_OBJ + tid];
    if (tid >= 64 && tid < 64 + N_OBJ) slab[tid - 64] = labels[n * N_OBJ + (tid - 64)];

    const int row = tid >> 2;
    const int q   = tid & 3;
    const int p   = r0 + row;
    const int psafe = (p < P_PRI) ? p : (P_PRI - 1);

    // ---- issue score loads early: lane q covers c = q, q+4, ..., q+76 ----
    const float* xrow = scores + (size_t)(n * P_PRI + psafe) * C_CLS;
    float v[20];
#pragma unroll
    for (int i = 0; i < 20; ++i) v[i] = xrow[q + 4 * i];
    float v80 = 0.0f;
    if (q == 0) v80 = xrow[80];

    // ---- prior box ----
    const float4 c = ((const float4*)priors)[psafe];
    const float px1 = c.x - c.z / 2.0f, py1 = c.y - c.w / 2.0f;
    const float px2 = c.x + c.z / 2.0f, py2 = c.y + c.w / 2.0f;
    const float pa  = (px2 - px1) * (py2 - py1);

    // ---- match: this lane handles objects [q*6, q*6+6) ----
    const float4* bxg = (const float4*)(boxes + (size_t)n * N_OBJ * 4);
    float bv = -1.0f;
    int   bo = q * 6;
#pragma unroll
    for (int j = 0; j < 6; ++j) {
        const int o = q * 6 + j;
        const float4 b = bxg[o];
        const float lox = fmaxf(b.x, px1), loy = fmaxf(b.y, py1);
        const float hix = fminf(b.z, px2), hiy = fminf(b.w, py2);
        const float iw = fmaxf(hix - lox, 0.0f), ih = fmaxf(hiy - loy, 0.0f);
        const float inter = iw * ih;
        const float ab = (b.z - b.x) * (b.w - b.y);
        const float iou = inter / (ab + pa - inter);
        if (iou > bv) { bv = iou; bo = o; }            // ascending keeps first max
    }
#pragma unroll
    for (int m = 1; m < 4; m <<= 1) {                  // quad combine: first-max
        const float v2 = __shfl_xor(bv, m);
        const int   o2 = __shfl_xor(bo, m);
        if (v2 > bv || (v2 == bv && o2 < bo)) { bv = v2; bo = o2; }
    }
    __syncthreads();                                   // pfo/slab visible

    // ---- forced-prior overwrite: lane scans its 6, keep largest matching o ----
    int fo = -1;
#pragma unroll
    for (int j = 0; j < 6; ++j) {
        const int o = q * 6 + j;
        if (pfo[o] == p) fo = o;                       // ascending: keeps largest
    }
#pragma unroll
    for (int m = 1; m < 4; m <<= 1) fo = max(fo, __shfl_xor(fo, m));

    const int   obj = (fo >= 0) ? fo : bo;
    const float ov  = (fo >= 0) ? 1.0f : bv;

    int cls = slab[obj];
    if (ov < 0.5f) cls = 0;

    // ---- exp-sum + x[cls] selection in one sweep ----
    float a0 = 0.0f, a1 = 0.0f, sel = 0.0f;
#pragma unroll
    for (int i = 0; i < 20; ++i) {
        const int cc = q + 4 * i;
        const float e = __expf(v[i]);
        if (i & 1) a1 += e; else a0 += e;
        sel += (cc == cls) ? v[i] : 0.0f;
    }
    float s = a0 + a1;
    if (q == 0) {
        s += __expf(v80);
        sel += (cls == 80) ? v80 : 0.0f;
    }
    s   += __shfl_xor(s, 1);
    s   += __shfl_xor(s, 2);
    sel += __shfl_xor(sel, 1);
    sel += __shfl_xor(sel, 2);                         // row total in all 4 lanes

    float confpos = 0.0f, locv = 0.0f;
    int   cnt1 = 0;
    if (q == 0 && row < rows) {
        const float conf = __logf(s) - sel;
        const bool pos = (cls != 0);
        conf_neg[n * P_PRI + p] = pos ? 0.0f : fmaxf(conf, 0.0f);
        if (pos) {
            cnt1 = 1;
            confpos = conf;
            const float4 g = ((const float4*)locs)[(size_t)n * P_PRI + p];
            const float cx = g.x * c.z / 10.0f + c.x;
            const float cy = g.y * c.w / 10.0f + c.y;
            const float w  = expf(g.z / 5.0f) * c.z;
            const float hh = expf(g.w / 5.0f) * c.w;
            const float b1x1 = cx - w / 2.0f, b1y1 = cy - hh / 2.0f;
            const float b1x2 = cx + w / 2.0f, b1y2 = cy + hh / 2.0f;

            const float4 tb = bxg[obj];
            const float w1 = b1x2 - b1x1, h1 = b1y2 - b1y1;
            const float w2 = tb.z - tb.x, h2 = tb.w - tb.y;
            const float area1 = w1 * h1,  area2 = w2 * h2;
            const float c1x = (b1x2 + b1x1) / 2.0f, c1y = (b1y2 + b1y1) / 2.0f;
            const float c2x = (tb.z + tb.x) / 2.0f, c2y = (tb.w + tb.y) / 2.0f;
            const float inw = fmaxf(fminf(b1x2, tb.z) - fmaxf(b1x1, tb.x), 0.0f);
            const float inh = fmaxf(fminf(b1y2, tb.w) - fmaxf(b1y1, tb.y), 0.0f);
            const float owd = fmaxf(fmaxf(b1x2, tb.z) - fminf(b1x1, tb.x), 0.0f);
            const float ohd = fmaxf(fmaxf(b1y2, tb.w) - fminf(b1y1, tb.y), 0.0f);
            const float inner_diag = (c2x - c1x) * (c2x - c1x) + (c2y - c1y) * (c2y - c1y);
            const float outer_diag = owd * owd + ohd * ohd;
            const float inner = inw * inh;
            const float iou = inner / (area1 + area2 - inner);
            const float K = 0.40528473456935108577551785283891f; // 4/pi^2
            const float dat = atanf(w2 / h2) - atanf(w1 / h1);
            const float vv = K * dat * dat;
            const float alpha = vv / (1.0f - iou + vv);
            locv = 1.0f - iou + inner_diag / outer_diag + alpha * vv;
        }
    }

    // ---- block reduction: shfl within wave, tiny LDS across 4 waves ----
#pragma unroll
    for (int off = 32; off > 0; off >>= 1) {
        confpos += __shfl_down(confpos, off);
        locv    += __shfl_down(locv, off);
        cnt1    += __shfl_down(cnt1, off);
    }
    const int wid = tid >> 6;
    if ((tid & 63) == 0) {
        wred[wid][0] = confpos; wred[wid][1] = locv; wred[wid][2] = (float)cnt1;
    }
    __syncthreads();
    if (tid == 0) {
        float a = 0.0f, b = 0.0f, d = 0.0f;
#pragma unroll
        for (int w2 = 0; w2 < 4; ++w2) { a += wred[w2][0]; b += wred[w2][1]; d += wred[w2][2]; }
        const int slot = n * gridDim.x + blockIdx.x;
        partial_conf[slot] = a;
        partial_loc [slot] = b;
        atomicAdd(&npos[n], (int)d);
    }
}

// ---------------------------------------------------------------------------
// Kernel 3: per image, exact top-k sum of conf_neg (k=3*n_pos) via 31-round
// bitwise radix-select; values in registers; ballot/popc counts; 1 barrier/rd.
// ---------------------------------------------------------------------------
__global__ void __launch_bounds__(BLKM)
k_mine(const float* __restrict__ conf_neg,
       const int*   __restrict__ npos,
       float* __restrict__ hardneg) {
    __shared__ int   wcnt[2][BLKM / 64];
    __shared__ float wsum[BLKM / 64];

    const int n    = blockIdx.x;
    const int tid  = threadIdx.x;
    const int wid  = tid >> 6;
    const int lane = tid & 63;

    unsigned v[9];
#pragma unroll
    for (int k = 0; k < 9; ++k) {
        const int p = tid + k * BLKM;
        v[k] = (p < P_PRI) ? __float_as_uint(conf_neg[n * P_PRI + p]) : 0u;
    }

    int k0 = 3 * npos[n];
    if (k0 > P_PRI) k0 = P_PRI;
    if (k0 <= 0) { if (tid == 0) hardneg[n] = 0.0f; return; }

    unsigned prefix = 0u;
    int kk = k0;
    for (int bit = 30; bit >= 0; --bit) {          // bit31 (sign) always 0
        const unsigned hi = (prefix >> bit) | 1u;
        int cnt = 0;
#pragma unroll
        for (int k = 0; k < 9; ++k)
            cnt += __popcll(__ballot((v[k] >> bit) == hi));
        if (lane == 0) wcnt[bit & 1][wid] = cnt;
        __syncthreads();
        int tot = 0;
#pragma unroll
        for (int w = 0; w < BLKM / 64; ++w) tot += wcnt[bit & 1][w];
        if (tot >= kk) prefix |= (1u << bit);
        else           kk -= tot;
    }

    float psum = 0.0f; int pcnt = 0;
#pragma unroll
    for (int k = 0; k < 9; ++k) {
        if (v[k] > prefix) { psum += __uint_as_float(v[k]); ++pcnt; }
    }
#pragma unroll
    for (int off = 32; off > 0; off >>= 1) {
        psum += __shfl_down(psum, off);
        pcnt += __shfl_down(pcnt, off);
    }
    __syncthreads();
    if (lane == 0) { wsum[wid] = psum; wcnt[0][wid] = pcnt; }
    __syncthreads();
    if (tid == 0) {
        float S = 0.0f; int C = 0;
#pragma unroll
        for (int w = 0; w < BLKM / 64; ++w) { S += wsum[w]; C += wcnt[0][w]; }
        hardneg[n] = S + (float)(k0 - C) * __uint_as_float(prefix);
    }
}

// ---------------------------------------------------------------------------
// Kernel 4: final deterministic reduction to the scalar loss.
// ---------------------------------------------------------------------------
__global__ void k_final(const float* __restrict__ partial_conf,
                        const float* __restrict__ partial_loc,
                        const int*   __restrict__ npos,
                        const float* __restrict__ hardneg,
                        float* __restrict__ out) {
    __shared__ float s1[BLK], s2[BLK], s3[BLK];
    __shared__ int   si[BLK];
    const int tid = threadIdx.x;

    float c = 0.0f, l = 0.0f, h = 0.0f;
    int np = 0;
    for (int i = tid; i < NBLK2; i += BLK) { c += partial_conf[i]; l += partial_loc[i]; }
    if (tid < N_IMG) { h = hardneg[tid]; np = npos[tid]; }

    s1[tid] = c; s2[tid] = l; s3[tid] = h; si[tid] = np;
    __syncthreads();
    for (int s = BLK / 2; s > 0; s >>= 1) {
        if (tid < s) { s1[tid] += s1[tid + s]; s2[tid] += s2[tid + s];
                       s3[tid] += s3[tid + s]; si[tid] += si[tid + s]; }
        __syncthreads();
    }
    if (tid == 0) {
        const float npt = (float)si[0];
        const float conf_loss = (s3[0] + s1[0]) / npt;
        const float loc_loss  = s2[0] / npt;
        out[0] = conf_loss + loc_loss;   // ALPHA = 1
    }
}

// ---------------------------------------------------------------------------
extern "C" void kernel_launch(void* const* d_in, const int* in_sizes, int n_in,
                              void* d_out, int out_size, void* d_ws, size_t ws_size,
                              hipStream_t stream) {
    const float* locs   = (const float*)d_in[0];  // [N,P,4]
    const float* scores = (const float*)d_in[1];  // [N,P,C]
    const float* boxes  = (const float*)d_in[2];  // [N,NOBJ,4]
    const int*   labels = (const int*)  d_in[3];  // [N,NOBJ]
    const float* priors = (const float*)d_in[4];  // [P,4]
    float* out = (float*)d_out;

    char* w = (char*)d_ws;
    float* conf_neg      = (float*)w; w += (size_t)N_IMG * P_PRI * 4;
    int*   prior_for_obj = (int*)w;   w += (size_t)N_IMG * N_OBJ * 4;
    int*   npos          = (int*)w;   w += (size_t)N_IMG * 4;
    float* partial_conf  = (float*)w; w += (size_t)NBLK2 * 4;
    float* partial_loc   = (float*)w; w += (size_t)NBLK2 * 4;
    float* hardneg       = (float*)w; w += (size_t)N_IMG * 4;

    dim3 gridO(N_OBJ, N_IMG);
    k_obj_match<<<gridO, BLK, 0, stream>>>(boxes, priors, prior_for_obj, npos);

    dim3 gridM(PB2, N_IMG);
    k_main<<<gridM, BLK, 0, stream>>>(locs, scores, boxes, labels, priors,
                                      prior_for_obj, conf_neg, npos,
                                      partial_conf, partial_loc);

    k_mine<<<N_IMG, BLKM, 0, stream>>>(conf_neg, npos, hardneg);

    k_final<<<1, BLK, 0, stream>>>(partial_conf, partial_loc, npos, hardneg, out);
}